// Round 8
// baseline (592.017 us; speedup 1.0000x reference)
//
#include <hip/hip_runtime.h>
#include <hip/hip_bf16.h>
#include <cstddef>

#define NRB 100000      // robot nodes
#define NBL 100000      // ball nodes
#define NEDGE 600000    // edges per edge type
#define NSEG 300000     // concatenated dst space: [rr | rb | br], 100k each
// dims: 128 -> 128 -> 64
// NOTE: harness delivers integer inputs as int32 (edge indices are const int*).
//
// LAYER-0 FEATURE TABLES ARE SLICE-MAJOR: y[s][row][16ch], s=0..7.
// Rationale (round 7 counters): wave-per-row gather = per-row shfl-reduction
// (32 inst) + per-edge overhead ~5 inst with avg degree 6 -> VALU 52%.
// Thread-per-(row,slice) gather: no reduction at all, ~7x fewer wave-inst
// per edge; slice = blockIdx.x&7 pins each slice to one XCD -> 3.2MB
// slice-table is L2-resident (vs 25.6MB thrash, FETCH 250MB).

typedef __attribute__((ext_vector_type(8))) short short8;
typedef __attribute__((ext_vector_type(4))) float floatx4;

// ---------------- CSR build (merged) ----------------

__global__ __launch_bounds__(256) void deg_all_kernel(const int* __restrict__ ei0,
                                                      const int* __restrict__ ei1,
                                                      const int* __restrict__ ei2,
                                                      int* __restrict__ deg) {
    int e = blockIdx.x * 256 + threadIdx.x;
    if (e >= NEDGE) return;
    const int* ei = (blockIdx.y == 0) ? ei0 : ((blockIdx.y == 1) ? ei1 : ei2);
    atomicAdd(&deg[blockIdx.y * 100000 + ei[NEDGE + e]], 1);
}

__global__ __launch_bounds__(256) void scan1_kernel(const int* __restrict__ deg,
                                                    int* __restrict__ rowstart,
                                                    int* __restrict__ bsum) {
    __shared__ int sh[256];
    int t = threadIdx.x, blk = blockIdx.x;
    int base = blk * 1024 + t * 4;
    int v0 = (base + 0 < NSEG) ? deg[base + 0] : 0;
    int v1 = (base + 1 < NSEG) ? deg[base + 1] : 0;
    int v2 = (base + 2 < NSEG) ? deg[base + 2] : 0;
    int v3 = (base + 3 < NSEG) ? deg[base + 3] : 0;
    int tsum = v0 + v1 + v2 + v3;
    sh[t] = tsum; __syncthreads();
    for (int off = 1; off < 256; off <<= 1) {
        int x = (t >= off) ? sh[t - off] : 0;
        __syncthreads();
        sh[t] += x;
        __syncthreads();
    }
    int excl = sh[t] - tsum;
    if (t == 255) bsum[blk] = sh[255];
    if (base + 0 <= NSEG) rowstart[base + 0] = excl;
    if (base + 1 <= NSEG) rowstart[base + 1] = excl + v0;
    if (base + 2 <= NSEG) rowstart[base + 2] = excl + v0 + v1;
    if (base + 3 <= NSEG) rowstart[base + 3] = excl + v0 + v1 + v2;
}

__global__ __launch_bounds__(512) void scan2_kernel(int* __restrict__ bsum, int nb) {
    __shared__ int sh[512];
    int t = threadIdx.x;
    int v = (t < nb) ? bsum[t] : 0;
    sh[t] = v; __syncthreads();
    for (int off = 1; off < 512; off <<= 1) {
        int x = (t >= off) ? sh[t - off] : 0;
        __syncthreads();
        sh[t] += x;
        __syncthreads();
    }
    if (t < nb) bsum[t] = sh[t] - v;   // exclusive
}

__global__ __launch_bounds__(256) void scan3_inv_kernel(int* __restrict__ rowstart,
                                                        const int* __restrict__ bsum,
                                                        const int* __restrict__ deg,
                                                        float* __restrict__ inv) {
    int t = threadIdx.x, blk = blockIdx.x;
    int add = bsum[blk];
    int base = blk * 1024 + t * 4;
    #pragma unroll
    for (int j = 0; j < 4; ++j) {
        if (base + j <= NSEG) rowstart[base + j] += add;
        if (base + j < NSEG) inv[base + j] = 1.0f / fmaxf((float)deg[base + j], 1.0f);
    }
}

__global__ __launch_bounds__(256) void fill_all_kernel(const int* __restrict__ ei0,
                                                       const int* __restrict__ ei1,
                                                       const int* __restrict__ ei2,
                                                       const int* __restrict__ rowstart,
                                                       int* __restrict__ cursor,
                                                       int* __restrict__ col) {
    int e = blockIdx.x * 256 + threadIdx.x;
    if (e >= NEDGE) return;
    const int* ei = (blockIdx.y == 0) ? ei0 : ((blockIdx.y == 1) ? ei1 : ei2);
    int src = ei[e];
    int g = blockIdx.y * 100000 + ei[NEDGE + e];
    int pos = atomicAdd(&cursor[g], 1);
    col[rowstart[g] + pos] = src;
}

// ---------------- weight prep (one launch) ----------------
// Weights in MFMA-FRAGMENT-PACKED layout (round 7: coalesced B-frag loads):
//   WTp[((ks*NT + nt)*64 + lane)*8 + e] = W[k][n],
//   n = nt*16 + (lane&15), k = ks*32 + (lane>>4)*8 + e, NT = dout/16.
__global__ __launch_bounds__(256) void wprep_all_kernel(
    const float* Wl0_rb, const float* Wl0_rr, const float* Wr0_rr, const float* Wr0_br,
    const float* Wl0_br, const float* Wr0_rb,
    const float* Wl1_br, const float* Wl1_rr, const float* Wr1_rr, const float* Wr1_br,
    const float* b0_rr, const float* b0_br, const float* b1_rr, const float* b1_br,
    __hip_bfloat16* WT1, __hip_bfloat16* WT2, __hip_bfloat16* WT3, __hip_bfloat16* WT4,
    float* bsum0, float* bsum1)
{
    int job = blockIdx.y;
    int t = blockIdx.x * 256 + threadIdx.x;
    if (job == 8) {
        if (t < 128) bsum0[t] = b0_rr[t] + b0_br[t];
        else if (t < 192) bsum1[t - 128] = b1_rr[t - 128] + b1_br[t - 128];
        return;
    }
    const float* A = nullptr; const float* B = nullptr;
    __hip_bfloat16* dst = nullptr; int dout = 128;
    switch (job) {
        case 0: A = Wl0_rb; dst = WT1;                 break;
        case 1: A = Wl0_rr; dst = WT1 + 128 * 128;     break;
        case 2: A = Wr0_rr; B = Wr0_br; dst = WT1 + 2 * 128 * 128; break;
        case 3: A = Wl0_br; dst = WT2;                 break;
        case 4: A = Wr0_rb; dst = WT2 + 128 * 128;     break;
        case 5: A = Wl1_br; dst = WT3;       dout = 64; break;
        case 6: A = Wl1_rr; dst = WT4;       dout = 64; break;
        case 7: A = Wr1_rr; B = Wr1_br; dst = WT4 + 64 * 128; dout = 64; break;
    }
    if (t >= dout * 128) return;
    int e = t & 7, lane = (t >> 3) & 63, g = t >> 9;
    int ks, nt;
    if (dout == 128) { ks = g >> 3; nt = g & 7; }
    else             { ks = g >> 2; nt = g & 3; }
    int n = nt * 16 + (lane & 15);
    int k = ks * 32 + (lane >> 4) * 8 + e;
    float v = A[k * dout + n];
    if (B != nullptr) v += B[k * dout + n];
    dst[t] = __float2bfloat16(v);
}

// ---------------- MFMA GEMMs ----------------
// Round-7 structure (proven): M-tile=64, staged As, slice loop, fragment-
// packed coalesced B, per-wave Es LDS transpose epilogue. THIS ROUND: gemm_l0
// stores outputs SLICE-MAJOR [8][NRB][16] (still 512B-contiguous, no RMW);
// gemm_l1 A-stage reassembles rows from slices (As contents identical).

union Pack8 { __hip_bfloat16 h[8]; int4 v; };

// Layer 0: BN=128. by=0: A=x_robot, slices {y_rb, y_rr, sr}; by=1: A=x_ball, {y_br, sb}.
__global__ __launch_bounds__(256, 4) void gemm_l0_kernel(
    const float* __restrict__ xr, const float* __restrict__ xb,
    const __hip_bfloat16* __restrict__ WT1, const __hip_bfloat16* __restrict__ WT2,
    __hip_bfloat16* __restrict__ y_rb, __hip_bfloat16* __restrict__ y_rr,
    __hip_bfloat16* __restrict__ sr,
    __hip_bfloat16* __restrict__ y_br, __hip_bfloat16* __restrict__ sb,
    const float* __restrict__ bsum0, const float* __restrict__ b0_rb)
{
    __shared__ __hip_bfloat16 As[64][136];   // 17408 B
    __shared__ float Es[4][16][68];          // 17408 B (per-wave epilogue stage)

    const int tid = threadIdx.x, bm = blockIdx.x, by = blockIdx.y;
    const float* A = (by == 0) ? xr : xb;
    const __hip_bfloat16* WT = (by == 0) ? WT1 : WT2;
    const int ns = (by == 0) ? 3 : 2;
    const int c = tid & 15, rbase = tid >> 4;

    #pragma unroll
    for (int p = 0; p < 4; ++p) {
        int r = p * 16 + rbase;
        int gr = bm * 64 + r;
        float4 u = make_float4(0.f, 0.f, 0.f, 0.f), v = make_float4(0.f, 0.f, 0.f, 0.f);
        if (gr < NRB) {
            const float* src = A + (size_t)gr * 128 + c * 8;
            u = *(const float4*)(src);
            v = *(const float4*)(src + 4);
        }
        Pack8 pk;
        *(__hip_bfloat162*)&pk.h[0] = __float22bfloat162_rn(make_float2(u.x, u.y));
        *(__hip_bfloat162*)&pk.h[2] = __float22bfloat162_rn(make_float2(u.z, u.w));
        *(__hip_bfloat162*)&pk.h[4] = __float22bfloat162_rn(make_float2(v.x, v.y));
        *(__hip_bfloat162*)&pk.h[6] = __float22bfloat162_rn(make_float2(v.z, v.w));
        *(int4*)&As[r][c * 8] = pk.v;
    }
    __syncthreads();

    const int wave = tid >> 6, lane = tid & 63;
    const int wm = wave >> 1, wn = wave & 1;   // 2 row-halves(32) x 2 col-halves(64)
    const int lrow = lane & 15, lquad = lane >> 4;

    for (int s = 0; s < ns; ++s) {
        const __hip_bfloat16* Wb = WT + (size_t)s * 128 * 128;
        floatx4 acc[2][4];
        #pragma unroll
        for (int mt = 0; mt < 2; ++mt)
            #pragma unroll
            for (int nt = 0; nt < 4; ++nt) acc[mt][nt] = (floatx4){0.f, 0.f, 0.f, 0.f};

        #pragma unroll
        for (int ks = 0; ks < 4; ++ks) {
            short8 bf[4];
            #pragma unroll
            for (int nt = 0; nt < 4; ++nt)
                bf[nt] = *(const short8*)(Wb + (size_t)((ks * 8 + wn * 4 + nt) * 64 + lane) * 8);
            #pragma unroll
            for (int mt = 0; mt < 2; ++mt) {
                short8 af = *(const short8*)&As[wm * 32 + mt * 16 + lrow][ks * 32 + lquad * 8];
                #pragma unroll
                for (int nt = 0; nt < 4; ++nt)
                    acc[mt][nt] = __builtin_amdgcn_mfma_f32_16x16x32_bf16(af, bf[nt], acc[mt][nt], 0, 0, 0);
            }
        }

        __hip_bfloat16* op; const float* bp = nullptr;
        if (by == 0) { op = (s == 0) ? y_rb : ((s == 1) ? y_rr : sr); if (s == 2) bp = bsum0; }
        else         { op = (s == 0) ? y_br : sb;                      if (s == 1) bp = b0_rb; }

        float bv[4];
        #pragma unroll
        for (int nt = 0; nt < 4; ++nt)
            bv[nt] = (bp != nullptr) ? bp[wn * 64 + nt * 16 + lrow] : 0.0f;

        #pragma unroll
        for (int mt = 0; mt < 2; ++mt) {
            #pragma unroll
            for (int nt = 0; nt < 4; ++nt)
                #pragma unroll
                for (int r4 = 0; r4 < 4; ++r4)
                    Es[wave][lquad * 4 + r4][nt * 16 + lrow] = acc[mt][nt][r4] + bv[nt];
            // slice-major store: wave's 64 cols = slices wn*4..wn*4+3;
            // per it: 2 slices x 16 rows x 2 halves; 512B contiguous per slice
            #pragma unroll
            for (int it = 0; it < 2; ++it) {
                int s_loc = it * 2 + (lane >> 5);     // 0..3
                int row = (lane >> 1) & 15;
                int half = lane & 1;
                const float* ep = &Es[wave][row][s_loc * 16 + half * 8];
                float4 u = *(const float4*)ep;
                float4 v = *(const float4*)(ep + 4);
                int grow = bm * 64 + wm * 32 + mt * 16 + row;
                if (grow < NRB) {
                    Pack8 pk;
                    pk.h[0] = __float2bfloat16(u.x); pk.h[1] = __float2bfloat16(u.y);
                    pk.h[2] = __float2bfloat16(u.z); pk.h[3] = __float2bfloat16(u.w);
                    pk.h[4] = __float2bfloat16(v.x); pk.h[5] = __float2bfloat16(v.y);
                    pk.h[6] = __float2bfloat16(v.z); pk.h[7] = __float2bfloat16(v.w);
                    *(int4*)(op + ((size_t)(wn * 4 + s_loc) * NRB + grow) * 16 + half * 8) = pk.v;
                }
            }
        }
    }
}

// Layer 1: BN=64. by=0: A=r (slice-major), slices {z_rr (bf16), out (fp32)};
// by=1: A=bl (slice-major), slice {z_br (bf16)}. z/out stay ROW-MAJOR.
__global__ __launch_bounds__(256, 4) void gemm_l1_kernel(
    const __hip_bfloat16* __restrict__ r, const __hip_bfloat16* __restrict__ bl,
    const __hip_bfloat16* __restrict__ WT3, const __hip_bfloat16* __restrict__ WT4,
    __hip_bfloat16* __restrict__ z_rr, __hip_bfloat16* __restrict__ z_br,
    float* __restrict__ out, const float* __restrict__ bsum1)
{
    __shared__ __hip_bfloat16 As[64][136];   // 17408 B
    __shared__ float Es[4][16][36];          // 9216 B

    const int tid = threadIdx.x, bm = blockIdx.x, by = blockIdx.y;
    const __hip_bfloat16* A = (by == 0) ? r : bl;
    const int ns = (by == 0) ? 2 : 1;
    const int c = tid & 15, rbase = tid >> 4;

    // A is slice-major [8][NRB][16]; ch c*8 -> slice c>>1, off (c&1)*8.
    // As contents identical to row-major staging.
    #pragma unroll
    for (int p = 0; p < 4; ++p) {
        int r_ = p * 16 + rbase;
        int gr = bm * 64 + r_;
        int4 u = make_int4(0, 0, 0, 0);
        if (gr < NRB) u = *(const int4*)(A + ((size_t)(c >> 1) * NRB + gr) * 16 + (c & 1) * 8);
        *(int4*)&As[r_][c * 8] = u;
    }
    __syncthreads();

    const int wave = tid >> 6, lane = tid & 63;
    const int wm = wave >> 1, wn = wave & 1;   // 2 row-halves(32) x 2 col-halves(32)
    const int lrow = lane & 15, lquad = lane >> 4;

    for (int s = 0; s < ns; ++s) {
        const __hip_bfloat16* Wb = (by == 1) ? WT3 : ((s == 0) ? WT4 : WT4 + 64 * 128);
        floatx4 acc[2][2];
        #pragma unroll
        for (int mt = 0; mt < 2; ++mt)
            #pragma unroll
            for (int nt = 0; nt < 2; ++nt) acc[mt][nt] = (floatx4){0.f, 0.f, 0.f, 0.f};

        #pragma unroll
        for (int ks = 0; ks < 4; ++ks) {
            short8 bf[2];
            #pragma unroll
            for (int nt = 0; nt < 2; ++nt)
                bf[nt] = *(const short8*)(Wb + (size_t)((ks * 4 + wn * 2 + nt) * 64 + lane) * 8);
            #pragma unroll
            for (int mt = 0; mt < 2; ++mt) {
                short8 af = *(const short8*)&As[wm * 32 + mt * 16 + lrow][ks * 32 + lquad * 8];
                #pragma unroll
                for (int nt = 0; nt < 2; ++nt)
                    acc[mt][nt] = __builtin_amdgcn_mfma_f32_16x16x32_bf16(af, bf[nt], acc[mt][nt], 0, 0, 0);
            }
        }

        const bool isf = (by == 0 && s == 1);
        float bv[2];
        #pragma unroll
        for (int nt = 0; nt < 2; ++nt)
            bv[nt] = isf ? bsum1[wn * 32 + nt * 16 + lrow] : 0.0f;

        #pragma unroll
        for (int mt = 0; mt < 2; ++mt) {
            #pragma unroll
            for (int nt = 0; nt < 2; ++nt)
                #pragma unroll
                for (int r4 = 0; r4 < 4; ++r4)
                    Es[wave][lquad * 4 + r4][nt * 16 + lrow] = acc[mt][nt][r4] + bv[nt];
            int row = lane >> 2, ch = lane & 3;
            float4 u = *(const float4*)&Es[wave][row][ch * 8];
            float4 v = *(const float4*)&Es[wave][row][ch * 8 + 4];
            int grow = bm * 64 + wm * 32 + mt * 16 + row;
            if (grow < NRB) {
                if (isf) {
                    float* p = out + (size_t)grow * 64 + wn * 32 + ch * 8;
                    *(float4*)p = u;
                    *(float4*)(p + 4) = v;
                } else {
                    __hip_bfloat16* op = (by == 0) ? z_rr : z_br;
                    Pack8 pk;
                    pk.h[0] = __float2bfloat16(u.x); pk.h[1] = __float2bfloat16(u.y);
                    pk.h[2] = __float2bfloat16(u.z); pk.h[3] = __float2bfloat16(u.w);
                    pk.h[4] = __float2bfloat16(v.x); pk.h[5] = __float2bfloat16(v.y);
                    pk.h[6] = __float2bfloat16(v.z); pk.h[7] = __float2bfloat16(v.w);
                    *(int4*)(op + (size_t)grow * 64 + wn * 32 + ch * 8) = pk.v;
                }
            }
        }
    }
}

// ---------------- layer-0 gather: thread-per-(row, slice) ----------------
// slice = blockIdx.x & 7 (consecutive bids -> different XCDs -> each XCD's
// working set = one 3.2MB slice table, L2-resident). Each THREAD owns one
// row's 16 channels of one slice: no cross-lane reduction, no shfl.
// Coalescing: rowstart/inv/self/out accesses are consecutive-row ->
// fully coalesced; col reads are per-lane sequential segments.

__device__ inline void facc8(const int4& u, float w, float* a) {
    float2 f0 = __bfloat1622float2(*(const __hip_bfloat162*)&u.x);
    float2 f1 = __bfloat1622float2(*(const __hip_bfloat162*)&u.y);
    float2 f2 = __bfloat1622float2(*(const __hip_bfloat162*)&u.z);
    float2 f3 = __bfloat1622float2(*(const __hip_bfloat162*)&u.w);
    a[0] = fmaf(w, f0.x, a[0]); a[1] = fmaf(w, f0.y, a[1]);
    a[2] = fmaf(w, f1.x, a[2]); a[3] = fmaf(w, f1.y, a[3]);
    a[4] = fmaf(w, f2.x, a[4]); a[5] = fmaf(w, f2.y, a[5]);
    a[6] = fmaf(w, f3.x, a[6]); a[7] = fmaf(w, f3.y, a[7]);
}

__device__ inline void unpack8(const int4& u, float* s) {
    float2 f0 = __bfloat1622float2(*(const __hip_bfloat162*)&u.x);
    float2 f1 = __bfloat1622float2(*(const __hip_bfloat162*)&u.y);
    float2 f2 = __bfloat1622float2(*(const __hip_bfloat162*)&u.z);
    float2 f3 = __bfloat1622float2(*(const __hip_bfloat162*)&u.w);
    s[0] = f0.x; s[1] = f0.y; s[2] = f1.x; s[3] = f1.y;
    s[4] = f2.x; s[5] = f2.y; s[6] = f3.x; s[7] = f3.y;
}

// by=0: r[row] = relu(inv_rr*sum y_rr + inv_br*sum y_br + sr)
// by=1: bl[row] = relu(inv_rb*sum y_rb + sb)
__global__ __launch_bounds__(256) void gather_l0_kernel(
    const __hip_bfloat16* __restrict__ y_rr, const __hip_bfloat16* __restrict__ y_br,
    const __hip_bfloat16* __restrict__ sr,
    const __hip_bfloat16* __restrict__ y_rb, const __hip_bfloat16* __restrict__ sb,
    const int* __restrict__ col, const int* __restrict__ rowstart,
    const float* __restrict__ inv,
    __hip_bfloat16* __restrict__ r_out, __hip_bfloat16* __restrict__ bl_out)
{
    const int sl = blockIdx.x & 7;
    const int row = (blockIdx.x >> 3) * 256 + threadIdx.x;
    if (row >= NRB) return;
    const size_t soff = (size_t)sl * NRB * 16;

    float a[16];
    #pragma unroll
    for (int k = 0; k < 16; ++k) a[k] = 0.f;

    const __hip_bfloat16* outb;
    int4 sv0, sv1;

    if (blockIdx.y == 0) {
        int s1 = rowstart[row],          e1 = rowstart[row + 1];
        int s2 = rowstart[200000 + row], e2 = rowstart[200000 + row + 1];
        float ia = inv[row], ib = inv[200000 + row];
        // hoisted self load (independent of gathers)
        sv0 = *(const int4*)(sr + soff + (size_t)row * 16);
        sv1 = *(const int4*)(sr + soff + (size_t)row * 16 + 8);
        const __hip_bfloat16* t1 = y_rr + soff;
        const __hip_bfloat16* t2 = y_br + soff;
        for (int i = s1; i < e1; ++i) {
            const __hip_bfloat16* p = t1 + (size_t)col[i] * 16;
            int4 u0 = *(const int4*)(p);
            int4 u1 = *(const int4*)(p + 8);
            facc8(u0, ia, a);
            facc8(u1, ia, a + 8);
        }
        for (int i = s2; i < e2; ++i) {
            const __hip_bfloat16* p = t2 + (size_t)col[i] * 16;
            int4 u0 = *(const int4*)(p);
            int4 u1 = *(const int4*)(p + 8);
            facc8(u0, ib, a);
            facc8(u1, ib, a + 8);
        }
        outb = nullptr;
        __hip_bfloat16* outp = r_out;
        float s8[16];
        unpack8(sv0, s8); unpack8(sv1, s8 + 8);
        Pack8 p0, p1;
        #pragma unroll
        for (int k = 0; k < 8; ++k) {
            p0.h[k] = __float2bfloat16(fmaxf(a[k] + s8[k], 0.f));
            p1.h[k] = __float2bfloat16(fmaxf(a[8 + k] + s8[8 + k], 0.f));
        }
        *(int4*)(outp + soff + (size_t)row * 16) = p0.v;
        *(int4*)(outp + soff + (size_t)row * 16 + 8) = p1.v;
    } else {
        int s1 = rowstart[100000 + row], e1 = rowstart[100000 + row + 1];
        float ia = inv[100000 + row];
        sv0 = *(const int4*)(sb + soff + (size_t)row * 16);
        sv1 = *(const int4*)(sb + soff + (size_t)row * 16 + 8);
        const __hip_bfloat16* t1 = y_rb + soff;
        for (int i = s1; i < e1; ++i) {
            const __hip_bfloat16* p = t1 + (size_t)col[i] * 16;
            int4 u0 = *(const int4*)(p);
            int4 u1 = *(const int4*)(p + 8);
            facc8(u0, ia, a);
            facc8(u1, ia, a + 8);
        }
        outb = nullptr;
        __hip_bfloat16* outp = bl_out;
        float s8[16];
        unpack8(sv0, s8); unpack8(sv1, s8 + 8);
        Pack8 p0, p1;
        #pragma unroll
        for (int k = 0; k < 8; ++k) {
            p0.h[k] = __float2bfloat16(fmaxf(a[k] + s8[k], 0.f));
            p1.h[k] = __float2bfloat16(fmaxf(a[8 + k] + s8[8 + k], 0.f));
        }
        *(int4*)(outp + soff + (size_t)row * 16) = p0.v;
        *(int4*)(outp + soff + (size_t)row * 16 + 8) = p1.v;
    }
    (void)outb;
}

// ---------------- layer-1 gather (row-major z, unchanged round-7 form) ----

__device__ inline void facc4(const int2& u, float w, float* a) {
    float2 f0 = __bfloat1622float2(*(const __hip_bfloat162*)&u.x);
    float2 f1 = __bfloat1622float2(*(const __hip_bfloat162*)&u.y);
    a[0] = fmaf(w, f0.x, a[0]); a[1] = fmaf(w, f0.y, a[1]);
    a[2] = fmaf(w, f1.x, a[2]); a[3] = fmaf(w, f1.y, a[3]);
}

__device__ inline void seg_gather4(const __hip_bfloat16* __restrict__ tab,
                                   const int* __restrict__ col,
                                   int s, int e, int q, int c, float w, float* a) {
    for (int i = s + q; i < e; i += 4) {
        int2 u = *(const int2*)(tab + (size_t)col[i] * 64 + c * 4);
        facc4(u, w, a);
    }
}

// out[row] += inv_rr*sum z_rr[col] + inv_br*sum z_br[col]  (64-d)
__global__ __launch_bounds__(256) void gather64_dual_kernel(
    const __hip_bfloat16* __restrict__ zrr, const __hip_bfloat16* __restrict__ zbr,
    const int* __restrict__ col, const int* __restrict__ rowstart,
    const float* __restrict__ inv, float* __restrict__ out)
{
    int row = blockIdx.x * 4 + (threadIdx.x >> 6);
    if (row >= NRB) return;
    int lane = threadIdx.x & 63;
    int q = lane >> 4, c = lane & 15;   // 16 lanes x 8B = 128B row

    int s1 = rowstart[row],          e1 = rowstart[row + 1];
    int s2 = rowstart[200000 + row], e2 = rowstart[200000 + row + 1];
    float ia = inv[row], ib = inv[200000 + row];

    // hoist the out-row RMW read (independent of gathers)
    float4 cur = make_float4(0.f, 0.f, 0.f, 0.f);
    if (q == 0) cur = *(const float4*)(out + (size_t)row * 64 + c * 4);

    float a[4];
    #pragma unroll
    for (int k = 0; k < 4; ++k) a[k] = 0.f;

    seg_gather4(zrr, col, s1, e1, q, c, ia, a);
    seg_gather4(zbr, col, s2, e2, q, c, ib, a);

    #pragma unroll
    for (int k = 0; k < 4; ++k) {
        a[k] += __shfl_xor(a[k], 16, 64);
        a[k] += __shfl_xor(a[k], 32, 64);
    }
    if (q == 0) {
        cur.x += a[0]; cur.y += a[1]; cur.z += a[2]; cur.w += a[3];
        *(float4*)(out + (size_t)row * 64 + c * 4) = cur;
    }
}

// ---------------- launch ----------------

extern "C" void kernel_launch(void* const* d_in, const int* in_sizes, int n_in,
                              void* d_out, int out_size, void* d_ws, size_t ws_size,
                              hipStream_t stream) {
    (void)in_sizes; (void)n_in; (void)out_size; (void)ws_size;

    const float* x_robot = (const float*)d_in[0];
    const float* x_ball  = (const float*)d_in[1];
    const int* ei_rr = (const int*)d_in[2];   // [2, E] int32
    const int* ei_rb = (const int*)d_in[3];
    const int* ei_br = (const int*)d_in[4];
    const float* Wl0_rr = (const float*)d_in[5];
    const float* Wr0_rr = (const float*)d_in[6];
    const float* b0_rr  = (const float*)d_in[7];
    const float* Wl0_rb = (const float*)d_in[8];
    const float* Wr0_rb = (const float*)d_in[9];
    const float* b0_rb  = (const float*)d_in[10];
    const float* Wl0_br = (const float*)d_in[11];
    const float* Wr0_br = (const float*)d_in[12];
    const float* b0_br  = (const float*)d_in[13];
    const float* Wl1_rr = (const float*)d_in[14];
    const float* Wr1_rr = (const float*)d_in[15];
    const float* b1_rr  = (const float*)d_in[16];
    // d_in[17..19] unused (ball output not returned)
    const float* Wl1_br = (const float*)d_in[20];
    const float* Wr1_br = (const float*)d_in[21];
    const float* b1_br  = (const float*)d_in[22];

    const size_t NBIG = (size_t)NRB * 128;
    __hip_bfloat16* S0 = (__hip_bfloat16*)d_ws;    // y_rb, later z_br
    __hip_bfloat16* S1 = S0 + NBIG;                // y_rr, later z_rr
    __hip_bfloat16* S2 = S1 + NBIG;                // y_br
    __hip_bfloat16* S3 = S2 + NBIG;                // sr, later bl
    __hip_bfloat16* S4 = S3 + NBIG;                // sb
    __hip_bfloat16* S5 = S4 + NBIG;                // r
    __hip_bfloat16* WT1 = S5 + NBIG;               // 384*128
    __hip_bfloat16* WT2 = WT1 + 384 * 128;         // 256*128
    __hip_bfloat16* WT3 = WT2 + 256 * 128;         // 64*128
    __hip_bfloat16* WT4 = WT3 + 64 * 128;          // 128*128
    int* col_all  = (int*)(WT4 + 128 * 128);       // 3*NEDGE
    int* deg      = col_all + 3 * NEDGE;           // NSEG
    int* cursor   = deg + NSEG;                    // NSEG (adjacent: one memset)
    int* rowstart = cursor + NSEG;                 // NSEG+32
    int* bsum     = rowstart + NSEG + 32;          // 512
    float* inv    = (float*)(bsum + 512);          // NSEG
    float* bsum0  = inv + NSEG;                    // 128
    float* bsum1  = bsum0 + 128;                   // 64

    __hip_bfloat16* y_rb = S0; __hip_bfloat16* z_br = S0;
    __hip_bfloat16* y_rr = S1; __hip_bfloat16* z_rr = S1;
    __hip_bfloat16* y_br = S2;
    __hip_bfloat16* sr = S3;   __hip_bfloat16* bl = S3;
    __hip_bfloat16* sb = S4;
    __hip_bfloat16* r  = S5;

    const int SCAN_BLOCKS = (NSEG + 1024) / 1024;  // 293
    const int eblocks = (NEDGE + 255) / 256;       // 2344
    const int gm64 = (NRB + 63) / 64;              // 1563
    const int rblocks = (NRB + 3) / 4;
    const int gsl = ((NRB + 255) / 256) * 8;       // 391*8 = 3128

    // ---- CSR build ----
    hipMemsetAsync(deg, 0, 2 * NSEG * sizeof(int), stream);
    deg_all_kernel<<<dim3(eblocks, 3), 256, 0, stream>>>(ei_rr, ei_rb, ei_br, deg);
    scan1_kernel<<<SCAN_BLOCKS, 256, 0, stream>>>(deg, rowstart, bsum);
    scan2_kernel<<<1, 512, 0, stream>>>(bsum, SCAN_BLOCKS);
    scan3_inv_kernel<<<SCAN_BLOCKS, 256, 0, stream>>>(rowstart, bsum, deg, inv);
    fill_all_kernel<<<dim3(eblocks, 3), 256, 0, stream>>>(ei_rr, ei_rb, ei_br,
        rowstart, cursor, col_all);

    // ---- weight prep ----
    wprep_all_kernel<<<dim3(64, 9), 256, 0, stream>>>(
        Wl0_rb, Wl0_rr, Wr0_rr, Wr0_br, Wl0_br, Wr0_rb,
        Wl1_br, Wl1_rr, Wr1_rr, Wr1_br,
        b0_rr, b0_br, b1_rr, b1_br,
        WT1, WT2, WT3, WT4, bsum0, bsum1);

    // ---- layer 0 ----
    gemm_l0_kernel<<<dim3(gm64, 2), 256, 0, stream>>>(x_robot, x_ball, WT1, WT2,
        y_rb, y_rr, sr, y_br, sb, bsum0, b0_rb);
    gather_l0_kernel<<<dim3(gsl, 2), 256, 0, stream>>>(y_rr, y_br, sr, y_rb, sb,
        col_all, rowstart, inv, r, bl);

    // ---- layer 1 ----
    gemm_l1_kernel<<<dim3(gm64, 2), 256, 0, stream>>>(r, bl, WT3, WT4, z_rr, z_br,
        (float*)d_out, bsum1);
    gather64_dual_kernel<<<rblocks, 256, 0, stream>>>(z_rr, z_br, col_all, rowstart,
        inv, (float*)d_out);
}

// Round 9
// 520.622 us; speedup vs baseline: 1.1371x; 1.1371x over previous
//
#include <hip/hip_runtime.h>
#include <hip/hip_bf16.h>
#include <cstddef>

#define NRB 100000      // robot nodes
#define NBL 100000      // ball nodes
#define NEDGE 600000    // edges per edge type
#define NSEG 300000     // concatenated dst space: [rr | rb | br], 100k each
// dims: 128 -> 128 -> 64
// NOTE: harness delivers integer inputs as int32 (edge indices are const int*).
//
// Round-8 lesson: slice-major tables amplify fetch (32B useful / 64B line);
// row-major + 16 lanes x 16B per edge uses full lines. Keep row-major.

typedef __attribute__((ext_vector_type(8))) short short8;
typedef __attribute__((ext_vector_type(4))) float floatx4;

// ---------------- CSR build (merged) ----------------

__global__ __launch_bounds__(256) void deg_all_kernel(const int* __restrict__ ei0,
                                                      const int* __restrict__ ei1,
                                                      const int* __restrict__ ei2,
                                                      int* __restrict__ deg) {
    int e = blockIdx.x * 256 + threadIdx.x;
    if (e >= NEDGE) return;
    const int* ei = (blockIdx.y == 0) ? ei0 : ((blockIdx.y == 1) ? ei1 : ei2);
    atomicAdd(&deg[blockIdx.y * 100000 + ei[NEDGE + e]], 1);
}

__global__ __launch_bounds__(256) void scan1_kernel(const int* __restrict__ deg,
                                                    int* __restrict__ rowstart,
                                                    int* __restrict__ bsum) {
    __shared__ int sh[256];
    int t = threadIdx.x, blk = blockIdx.x;
    int base = blk * 1024 + t * 4;
    int v0 = (base + 0 < NSEG) ? deg[base + 0] : 0;
    int v1 = (base + 1 < NSEG) ? deg[base + 1] : 0;
    int v2 = (base + 2 < NSEG) ? deg[base + 2] : 0;
    int v3 = (base + 3 < NSEG) ? deg[base + 3] : 0;
    int tsum = v0 + v1 + v2 + v3;
    sh[t] = tsum; __syncthreads();
    for (int off = 1; off < 256; off <<= 1) {
        int x = (t >= off) ? sh[t - off] : 0;
        __syncthreads();
        sh[t] += x;
        __syncthreads();
    }
    int excl = sh[t] - tsum;
    if (t == 255) bsum[blk] = sh[255];
    if (base + 0 <= NSEG) rowstart[base + 0] = excl;
    if (base + 1 <= NSEG) rowstart[base + 1] = excl + v0;
    if (base + 2 <= NSEG) rowstart[base + 2] = excl + v0 + v1;
    if (base + 3 <= NSEG) rowstart[base + 3] = excl + v0 + v1 + v2;
}

__global__ __launch_bounds__(512) void scan2_kernel(int* __restrict__ bsum, int nb) {
    __shared__ int sh[512];
    int t = threadIdx.x;
    int v = (t < nb) ? bsum[t] : 0;
    sh[t] = v; __syncthreads();
    for (int off = 1; off < 512; off <<= 1) {
        int x = (t >= off) ? sh[t - off] : 0;
        __syncthreads();
        sh[t] += x;
        __syncthreads();
    }
    if (t < nb) bsum[t] = sh[t] - v;   // exclusive
}

__global__ __launch_bounds__(256) void scan3_inv_kernel(int* __restrict__ rowstart,
                                                        const int* __restrict__ bsum,
                                                        const int* __restrict__ deg,
                                                        float* __restrict__ inv) {
    int t = threadIdx.x, blk = blockIdx.x;
    int add = bsum[blk];
    int base = blk * 1024 + t * 4;
    #pragma unroll
    for (int j = 0; j < 4; ++j) {
        if (base + j <= NSEG) rowstart[base + j] += add;
        if (base + j < NSEG) inv[base + j] = 1.0f / fmaxf((float)deg[base + j], 1.0f);
    }
}

__global__ __launch_bounds__(256) void fill_all_kernel(const int* __restrict__ ei0,
                                                       const int* __restrict__ ei1,
                                                       const int* __restrict__ ei2,
                                                       const int* __restrict__ rowstart,
                                                       int* __restrict__ cursor,
                                                       int* __restrict__ col) {
    int e = blockIdx.x * 256 + threadIdx.x;
    if (e >= NEDGE) return;
    const int* ei = (blockIdx.y == 0) ? ei0 : ((blockIdx.y == 1) ? ei1 : ei2);
    int src = ei[e];
    int g = blockIdx.y * 100000 + ei[NEDGE + e];
    int pos = atomicAdd(&cursor[g], 1);
    col[rowstart[g] + pos] = src;
}

// ---------------- weight prep (one launch) ----------------
// Weights in MFMA-FRAGMENT-PACKED layout (round 7: coalesced B-frag loads):
//   WTp[((ks*NT + nt)*64 + lane)*8 + e] = W[k][n],
//   n = nt*16 + (lane&15), k = ks*32 + (lane>>4)*8 + e, NT = dout/16.
__global__ __launch_bounds__(256) void wprep_all_kernel(
    const float* Wl0_rb, const float* Wl0_rr, const float* Wr0_rr, const float* Wr0_br,
    const float* Wl0_br, const float* Wr0_rb,
    const float* Wl1_br, const float* Wl1_rr, const float* Wr1_rr, const float* Wr1_br,
    const float* b0_rr, const float* b0_br, const float* b1_rr, const float* b1_br,
    __hip_bfloat16* WT1, __hip_bfloat16* WT2, __hip_bfloat16* WT3, __hip_bfloat16* WT4,
    float* bsum0, float* bsum1)
{
    int job = blockIdx.y;
    int t = blockIdx.x * 256 + threadIdx.x;
    if (job == 8) {
        if (t < 128) bsum0[t] = b0_rr[t] + b0_br[t];
        else if (t < 192) bsum1[t - 128] = b1_rr[t - 128] + b1_br[t - 128];
        return;
    }
    const float* A = nullptr; const float* B = nullptr;
    __hip_bfloat16* dst = nullptr; int dout = 128;
    switch (job) {
        case 0: A = Wl0_rb; dst = WT1;                 break;
        case 1: A = Wl0_rr; dst = WT1 + 128 * 128;     break;
        case 2: A = Wr0_rr; B = Wr0_br; dst = WT1 + 2 * 128 * 128; break;
        case 3: A = Wl0_br; dst = WT2;                 break;
        case 4: A = Wr0_rb; dst = WT2 + 128 * 128;     break;
        case 5: A = Wl1_br; dst = WT3;       dout = 64; break;
        case 6: A = Wl1_rr; dst = WT4;       dout = 64; break;
        case 7: A = Wr1_rr; B = Wr1_br; dst = WT4 + 64 * 128; dout = 64; break;
    }
    if (t >= dout * 128) return;
    int e = t & 7, lane = (t >> 3) & 63, g = t >> 9;
    int ks, nt;
    if (dout == 128) { ks = g >> 3; nt = g & 7; }
    else             { ks = g >> 2; nt = g & 3; }
    int n = nt * 16 + (lane & 15);
    int k = ks * 32 + (lane >> 4) * 8 + e;
    float v = A[k * dout + n];
    if (B != nullptr) v += B[k * dout + n];
    dst[t] = __float2bfloat16(v);
}

// ---------------- MFMA GEMMs (round-7 proven form, unchanged) ----------------
// M-tile=64, staged As, slice loop (A staged once), fragment-packed coalesced
// B, per-wave Es LDS transpose epilogue (16B/lane contiguous stores).

union Pack8 { __hip_bfloat16 h[8]; int4 v; };

// Layer 0: BN=128. by=0: A=x_robot, slices {y_rb, y_rr, sr}; by=1: A=x_ball, {y_br, sb}.
__global__ __launch_bounds__(256, 4) void gemm_l0_kernel(
    const float* __restrict__ xr, const float* __restrict__ xb,
    const __hip_bfloat16* __restrict__ WT1, const __hip_bfloat16* __restrict__ WT2,
    __hip_bfloat16* __restrict__ y_rb, __hip_bfloat16* __restrict__ y_rr,
    __hip_bfloat16* __restrict__ sr,
    __hip_bfloat16* __restrict__ y_br, __hip_bfloat16* __restrict__ sb,
    const float* __restrict__ bsum0, const float* __restrict__ b0_rb)
{
    __shared__ __hip_bfloat16 As[64][136];   // 17408 B
    __shared__ float Es[4][16][68];          // 17408 B (per-wave epilogue stage)

    const int tid = threadIdx.x, bm = blockIdx.x, by = blockIdx.y;
    const float* A = (by == 0) ? xr : xb;
    const __hip_bfloat16* WT = (by == 0) ? WT1 : WT2;
    const int ns = (by == 0) ? 3 : 2;
    const int c = tid & 15, rbase = tid >> 4;

    #pragma unroll
    for (int p = 0; p < 4; ++p) {
        int r = p * 16 + rbase;
        int gr = bm * 64 + r;
        float4 u = make_float4(0.f, 0.f, 0.f, 0.f), v = make_float4(0.f, 0.f, 0.f, 0.f);
        if (gr < NRB) {
            const float* src = A + (size_t)gr * 128 + c * 8;
            u = *(const float4*)(src);
            v = *(const float4*)(src + 4);
        }
        Pack8 pk;
        *(__hip_bfloat162*)&pk.h[0] = __float22bfloat162_rn(make_float2(u.x, u.y));
        *(__hip_bfloat162*)&pk.h[2] = __float22bfloat162_rn(make_float2(u.z, u.w));
        *(__hip_bfloat162*)&pk.h[4] = __float22bfloat162_rn(make_float2(v.x, v.y));
        *(__hip_bfloat162*)&pk.h[6] = __float22bfloat162_rn(make_float2(v.z, v.w));
        *(int4*)&As[r][c * 8] = pk.v;
    }
    __syncthreads();

    const int wave = tid >> 6, lane = tid & 63;
    const int wm = wave >> 1, wn = wave & 1;   // 2 row-halves(32) x 2 col-halves(64)
    const int lrow = lane & 15, lquad = lane >> 4;

    for (int s = 0; s < ns; ++s) {
        const __hip_bfloat16* Wb = WT + (size_t)s * 128 * 128;
        floatx4 acc[2][4];
        #pragma unroll
        for (int mt = 0; mt < 2; ++mt)
            #pragma unroll
            for (int nt = 0; nt < 4; ++nt) acc[mt][nt] = (floatx4){0.f, 0.f, 0.f, 0.f};

        #pragma unroll
        for (int ks = 0; ks < 4; ++ks) {
            short8 bf[4];
            #pragma unroll
            for (int nt = 0; nt < 4; ++nt)
                bf[nt] = *(const short8*)(Wb + (size_t)((ks * 8 + wn * 4 + nt) * 64 + lane) * 8);
            #pragma unroll
            for (int mt = 0; mt < 2; ++mt) {
                short8 af = *(const short8*)&As[wm * 32 + mt * 16 + lrow][ks * 32 + lquad * 8];
                #pragma unroll
                for (int nt = 0; nt < 4; ++nt)
                    acc[mt][nt] = __builtin_amdgcn_mfma_f32_16x16x32_bf16(af, bf[nt], acc[mt][nt], 0, 0, 0);
            }
        }

        __hip_bfloat16* op; const float* bp = nullptr;
        if (by == 0) { op = (s == 0) ? y_rb : ((s == 1) ? y_rr : sr); if (s == 2) bp = bsum0; }
        else         { op = (s == 0) ? y_br : sb;                      if (s == 1) bp = b0_rb; }

        float bv[4];
        #pragma unroll
        for (int nt = 0; nt < 4; ++nt)
            bv[nt] = (bp != nullptr) ? bp[wn * 64 + nt * 16 + lrow] : 0.0f;

        #pragma unroll
        for (int mt = 0; mt < 2; ++mt) {
            #pragma unroll
            for (int nt = 0; nt < 4; ++nt)
                #pragma unroll
                for (int r4 = 0; r4 < 4; ++r4)
                    Es[wave][lquad * 4 + r4][nt * 16 + lrow] = acc[mt][nt][r4] + bv[nt];
            #pragma unroll
            for (int it = 0; it < 2; ++it) {
                int row = it * 8 + (lane >> 3);
                int ch = lane & 7;
                float4 u = *(const float4*)&Es[wave][row][ch * 8];
                float4 v = *(const float4*)&Es[wave][row][ch * 8 + 4];
                int grow = bm * 64 + wm * 32 + mt * 16 + row;
                if (grow < NRB) {
                    Pack8 pk;
                    pk.h[0] = __float2bfloat16(u.x); pk.h[1] = __float2bfloat16(u.y);
                    pk.h[2] = __float2bfloat16(u.z); pk.h[3] = __float2bfloat16(u.w);
                    pk.h[4] = __float2bfloat16(v.x); pk.h[5] = __float2bfloat16(v.y);
                    pk.h[6] = __float2bfloat16(v.z); pk.h[7] = __float2bfloat16(v.w);
                    *(int4*)(op + (size_t)grow * 128 + wn * 64 + ch * 8) = pk.v;
                }
            }
        }
    }
}

// Layer 1: BN=64. by=0: A=r, slices {z_rr (bf16), out=r@Wsum1+bsum1 (fp32)};
// by=1: A=bl, slice {z_br (bf16)}.
__global__ __launch_bounds__(256, 4) void gemm_l1_kernel(
    const __hip_bfloat16* __restrict__ r, const __hip_bfloat16* __restrict__ bl,
    const __hip_bfloat16* __restrict__ WT3, const __hip_bfloat16* __restrict__ WT4,
    __hip_bfloat16* __restrict__ z_rr, __hip_bfloat16* __restrict__ z_br,
    float* __restrict__ out, const float* __restrict__ bsum1)
{
    __shared__ __hip_bfloat16 As[64][136];   // 17408 B
    __shared__ float Es[4][16][36];          // 9216 B

    const int tid = threadIdx.x, bm = blockIdx.x, by = blockIdx.y;
    const __hip_bfloat16* A = (by == 0) ? r : bl;
    const int ns = (by == 0) ? 2 : 1;
    const int c = tid & 15, rbase = tid >> 4;

    #pragma unroll
    for (int p = 0; p < 4; ++p) {
        int r_ = p * 16 + rbase;
        int gr = bm * 64 + r_;
        int4 u = make_int4(0, 0, 0, 0);
        if (gr < NRB) u = *(const int4*)(A + (size_t)gr * 128 + c * 8);
        *(int4*)&As[r_][c * 8] = u;
    }
    __syncthreads();

    const int wave = tid >> 6, lane = tid & 63;
    const int wm = wave >> 1, wn = wave & 1;   // 2 row-halves(32) x 2 col-halves(32)
    const int lrow = lane & 15, lquad = lane >> 4;

    for (int s = 0; s < ns; ++s) {
        const __hip_bfloat16* Wb = (by == 1) ? WT3 : ((s == 0) ? WT4 : WT4 + 64 * 128);
        floatx4 acc[2][2];
        #pragma unroll
        for (int mt = 0; mt < 2; ++mt)
            #pragma unroll
            for (int nt = 0; nt < 2; ++nt) acc[mt][nt] = (floatx4){0.f, 0.f, 0.f, 0.f};

        #pragma unroll
        for (int ks = 0; ks < 4; ++ks) {
            short8 bf[2];
            #pragma unroll
            for (int nt = 0; nt < 2; ++nt)
                bf[nt] = *(const short8*)(Wb + (size_t)((ks * 4 + wn * 2 + nt) * 64 + lane) * 8);
            #pragma unroll
            for (int mt = 0; mt < 2; ++mt) {
                short8 af = *(const short8*)&As[wm * 32 + mt * 16 + lrow][ks * 32 + lquad * 8];
                #pragma unroll
                for (int nt = 0; nt < 2; ++nt)
                    acc[mt][nt] = __builtin_amdgcn_mfma_f32_16x16x32_bf16(af, bf[nt], acc[mt][nt], 0, 0, 0);
            }
        }

        const bool isf = (by == 0 && s == 1);
        float bv[2];
        #pragma unroll
        for (int nt = 0; nt < 2; ++nt)
            bv[nt] = isf ? bsum1[wn * 32 + nt * 16 + lrow] : 0.0f;

        #pragma unroll
        for (int mt = 0; mt < 2; ++mt) {
            #pragma unroll
            for (int nt = 0; nt < 2; ++nt)
                #pragma unroll
                for (int r4 = 0; r4 < 4; ++r4)
                    Es[wave][lquad * 4 + r4][nt * 16 + lrow] = acc[mt][nt][r4] + bv[nt];
            int row = lane >> 2, ch = lane & 3;
            float4 u = *(const float4*)&Es[wave][row][ch * 8];
            float4 v = *(const float4*)&Es[wave][row][ch * 8 + 4];
            int grow = bm * 64 + wm * 32 + mt * 16 + row;
            if (grow < NRB) {
                if (isf) {
                    float* p = out + (size_t)grow * 64 + wn * 32 + ch * 8;
                    *(float4*)p = u;
                    *(float4*)(p + 4) = v;
                } else {
                    __hip_bfloat16* op = (by == 0) ? z_rr : z_br;
                    Pack8 pk;
                    pk.h[0] = __float2bfloat16(u.x); pk.h[1] = __float2bfloat16(u.y);
                    pk.h[2] = __float2bfloat16(u.z); pk.h[3] = __float2bfloat16(u.w);
                    pk.h[4] = __float2bfloat16(v.x); pk.h[5] = __float2bfloat16(v.y);
                    pk.h[6] = __float2bfloat16(v.z); pk.h[7] = __float2bfloat16(v.w);
                    *(int4*)(op + (size_t)grow * 64 + wn * 32 + ch * 8) = pk.v;
                }
            }
        }
    }
}

// ---------------- gathers (2 rows/wave, col-prefetch pipeline) ----------------
// Round-7 per-row budget: ~90 prologue/epilogue + 32 shfl + ~60 loop inst.
// 2 rows per wave (half-wave of 32 lanes each, 2 groups of 16 walking
// every-2nd edge) shares prologue/epilogue across rows and cuts the
// reduction to ONE shfl_xor(16) — ~30% fewer wave-inst/row. Rotated loop
// prefetches col[i+2] before the dependent row load (no duplicate loads).
// Full-line reads preserved: 16 lanes x 16B (l0) / 8B (l1) per edge.

__device__ inline void facc8(const int4& u, float w, float* a) {
    float2 f0 = __bfloat1622float2(*(const __hip_bfloat162*)&u.x);
    float2 f1 = __bfloat1622float2(*(const __hip_bfloat162*)&u.y);
    float2 f2 = __bfloat1622float2(*(const __hip_bfloat162*)&u.z);
    float2 f3 = __bfloat1622float2(*(const __hip_bfloat162*)&u.w);
    a[0] = fmaf(w, f0.x, a[0]); a[1] = fmaf(w, f0.y, a[1]);
    a[2] = fmaf(w, f1.x, a[2]); a[3] = fmaf(w, f1.y, a[3]);
    a[4] = fmaf(w, f2.x, a[4]); a[5] = fmaf(w, f2.y, a[5]);
    a[6] = fmaf(w, f3.x, a[6]); a[7] = fmaf(w, f3.y, a[7]);
}

__device__ inline void unpack8(const int4& u, float* s) {
    float2 f0 = __bfloat1622float2(*(const __hip_bfloat162*)&u.x);
    float2 f1 = __bfloat1622float2(*(const __hip_bfloat162*)&u.y);
    float2 f2 = __bfloat1622float2(*(const __hip_bfloat162*)&u.z);
    float2 f3 = __bfloat1622float2(*(const __hip_bfloat162*)&u.w);
    s[0] = f0.x; s[1] = f0.y; s[2] = f1.x; s[3] = f1.y;
    s[4] = f2.x; s[5] = f2.y; s[6] = f3.x; s[7] = f3.y;
}

// gather over one CSR segment, 2 groups of 16 per row, step 2, col prefetch
__device__ inline void seg_gather8(const __hip_bfloat16* __restrict__ tab,
                                   const int* __restrict__ col,
                                   int s, int e, int q, int c, float w, float* a) {
    int i = s + q;
    if (i >= e) return;
    int cj = col[i];
    i += 2;
    for (; i < e; i += 2) {
        int cn = col[i];                        // next col issues first
        int4 u = *(const int4*)(tab + (size_t)cj * 128 + c * 8);
        facc8(u, w, a);
        cj = cn;
    }
    int4 u = *(const int4*)(tab + (size_t)cj * 128 + c * 8);
    facc8(u, w, a);
}

// by=0: r[row] = relu(inv_rr*sum y_rr + inv_br*sum y_br + sr)
// by=1: bl[row] = relu(inv_rb*sum y_rb + sb)
__global__ __launch_bounds__(256) void gather_l0_kernel(
    const __hip_bfloat16* __restrict__ y_rr, const __hip_bfloat16* __restrict__ y_br,
    const __hip_bfloat16* __restrict__ sr,
    const __hip_bfloat16* __restrict__ y_rb, const __hip_bfloat16* __restrict__ sb,
    const int* __restrict__ col, const int* __restrict__ rowstart,
    const float* __restrict__ inv,
    __hip_bfloat16* __restrict__ r_out, __hip_bfloat16* __restrict__ bl_out)
{
    int row = blockIdx.x * 8 + (threadIdx.x >> 5);   // 2 rows per wave
    if (row >= NRB) return;
    int hl = threadIdx.x & 31;
    int q = hl >> 4, c = hl & 15;    // 2 groups of 16 lanes per row

    float a[8];
    #pragma unroll
    for (int k = 0; k < 8; ++k) a[k] = 0.f;

    const __hip_bfloat16* self;
    __hip_bfloat16* outp;
    int4 sv = make_int4(0, 0, 0, 0);

    if (blockIdx.y == 0) {
        int s1 = rowstart[row],          e1 = rowstart[row + 1];
        int s2 = rowstart[200000 + row], e2 = rowstart[200000 + row + 1];
        float ia = inv[row], ib = inv[200000 + row];
        self = sr; outp = r_out;
        if (q == 0) sv = *(const int4*)(self + (size_t)row * 128 + c * 8);
        seg_gather8(y_rr, col, s1, e1, q, c, ia, a);
        seg_gather8(y_br, col, s2, e2, q, c, ib, a);
    } else {
        int s1 = rowstart[100000 + row], e1 = rowstart[100000 + row + 1];
        float ia = inv[100000 + row];
        self = sb; outp = bl_out;
        if (q == 0) sv = *(const int4*)(self + (size_t)row * 128 + c * 8);
        seg_gather8(y_rb, col, s1, e1, q, c, ia, a);
    }

    // combine the two 16-lane groups (xor 16 stays within each half-wave)
    #pragma unroll
    for (int k = 0; k < 8; ++k)
        a[k] += __shfl_xor(a[k], 16, 64);

    if (q == 0) {
        float s8[8];
        unpack8(sv, s8);
        Pack8 pk;
        #pragma unroll
        for (int k = 0; k < 8; ++k)
            pk.h[k] = __float2bfloat16(fmaxf(a[k] + s8[k], 0.f));
        *(int4*)(outp + (size_t)row * 128 + c * 8) = pk.v;
    }
}

__device__ inline void facc4(const int2& u, float w, float* a) {
    float2 f0 = __bfloat1622float2(*(const __hip_bfloat162*)&u.x);
    float2 f1 = __bfloat1622float2(*(const __hip_bfloat162*)&u.y);
    a[0] = fmaf(w, f0.x, a[0]); a[1] = fmaf(w, f0.y, a[1]);
    a[2] = fmaf(w, f1.x, a[2]); a[3] = fmaf(w, f1.y, a[3]);
}

__device__ inline void seg_gather4(const __hip_bfloat16* __restrict__ tab,
                                   const int* __restrict__ col,
                                   int s, int e, int q, int c, float w, float* a) {
    int i = s + q;
    if (i >= e) return;
    int cj = col[i];
    i += 2;
    for (; i < e; i += 2) {
        int cn = col[i];
        int2 u = *(const int2*)(tab + (size_t)cj * 64 + c * 4);
        facc4(u, w, a);
        cj = cn;
    }
    int2 u = *(const int2*)(tab + (size_t)cj * 64 + c * 4);
    facc4(u, w, a);
}

// out[row] += inv_rr*sum z_rr[col] + inv_br*sum z_br[col]  (64-d)
__global__ __launch_bounds__(256) void gather64_dual_kernel(
    const __hip_bfloat16* __restrict__ zrr, const __hip_bfloat16* __restrict__ zbr,
    const int* __restrict__ col, const int* __restrict__ rowstart,
    const float* __restrict__ inv, float* __restrict__ out)
{
    int row = blockIdx.x * 8 + (threadIdx.x >> 5);   // 2 rows per wave
    if (row >= NRB) return;
    int hl = threadIdx.x & 31;
    int q = hl >> 4, c = hl & 15;    // 16 lanes x 8B = 128B row

    int s1 = rowstart[row],          e1 = rowstart[row + 1];
    int s2 = rowstart[200000 + row], e2 = rowstart[200000 + row + 1];
    float ia = inv[row], ib = inv[200000 + row];

    // hoist the out-row RMW read (independent of gathers)
    float4 cur = make_float4(0.f, 0.f, 0.f, 0.f);
    if (q == 0) cur = *(const float4*)(out + (size_t)row * 64 + c * 4);

    float a[4];
    #pragma unroll
    for (int k = 0; k < 4; ++k) a[k] = 0.f;

    seg_gather4(zrr, col, s1, e1, q, c, ia, a);
    seg_gather4(zbr, col, s2, e2, q, c, ib, a);

    #pragma unroll
    for (int k = 0; k < 4; ++k)
        a[k] += __shfl_xor(a[k], 16, 64);

    if (q == 0) {
        cur.x += a[0]; cur.y += a[1]; cur.z += a[2]; cur.w += a[3];
        *(float4*)(out + (size_t)row * 64 + c * 4) = cur;
    }
}

// ---------------- launch ----------------

extern "C" void kernel_launch(void* const* d_in, const int* in_sizes, int n_in,
                              void* d_out, int out_size, void* d_ws, size_t ws_size,
                              hipStream_t stream) {
    (void)in_sizes; (void)n_in; (void)out_size; (void)ws_size;

    const float* x_robot = (const float*)d_in[0];
    const float* x_ball  = (const float*)d_in[1];
    const int* ei_rr = (const int*)d_in[2];   // [2, E] int32
    const int* ei_rb = (const int*)d_in[3];
    const int* ei_br = (const int*)d_in[4];
    const float* Wl0_rr = (const float*)d_in[5];
    const float* Wr0_rr = (const float*)d_in[6];
    const float* b0_rr  = (const float*)d_in[7];
    const float* Wl0_rb = (const float*)d_in[8];
    const float* Wr0_rb = (const float*)d_in[9];
    const float* b0_rb  = (const float*)d_in[10];
    const float* Wl0_br = (const float*)d_in[11];
    const float* Wr0_br = (const float*)d_in[12];
    const float* b0_br  = (const float*)d_in[13];
    const float* Wl1_rr = (const float*)d_in[14];
    const float* Wr1_rr = (const float*)d_in[15];
    const float* b1_rr  = (const float*)d_in[16];
    // d_in[17..19] unused (ball output not returned)
    const float* Wl1_br = (const float*)d_in[20];
    const float* Wr1_br = (const float*)d_in[21];
    const float* b1_br  = (const float*)d_in[22];

    const size_t NBIG = (size_t)NRB * 128;
    __hip_bfloat16* S0 = (__hip_bfloat16*)d_ws;    // y_rb, later z_br
    __hip_bfloat16* S1 = S0 + NBIG;                // y_rr, later z_rr
    __hip_bfloat16* S2 = S1 + NBIG;                // y_br
    __hip_bfloat16* S3 = S2 + NBIG;                // sr, later bl
    __hip_bfloat16* S4 = S3 + NBIG;                // sb
    __hip_bfloat16* S5 = S4 + NBIG;                // r
    __hip_bfloat16* WT1 = S5 + NBIG;               // 384*128
    __hip_bfloat16* WT2 = WT1 + 384 * 128;         // 256*128
    __hip_bfloat16* WT3 = WT2 + 256 * 128;         // 64*128
    __hip_bfloat16* WT4 = WT3 + 64 * 128;          // 128*128
    int* col_all  = (int*)(WT4 + 128 * 128);       // 3*NEDGE
    int* deg      = col_all + 3 * NEDGE;           // NSEG
    int* cursor   = deg + NSEG;                    // NSEG (adjacent: one memset)
    int* rowstart = cursor + NSEG;                 // NSEG+32
    int* bsum     = rowstart + NSEG + 32;          // 512
    float* inv    = (float*)(bsum + 512);          // NSEG
    float* bsum0  = inv + NSEG;                    // 128
    float* bsum1  = bsum0 + 128;                   // 64

    __hip_bfloat16* y_rb = S0; __hip_bfloat16* z_br = S0;
    __hip_bfloat16* y_rr = S1; __hip_bfloat16* z_rr = S1;
    __hip_bfloat16* y_br = S2;
    __hip_bfloat16* sr = S3;   __hip_bfloat16* bl = S3;
    __hip_bfloat16* sb = S4;
    __hip_bfloat16* r  = S5;

    const int SCAN_BLOCKS = (NSEG + 1024) / 1024;  // 293
    const int eblocks = (NEDGE + 255) / 256;       // 2344
    const int gm64 = (NRB + 63) / 64;              // 1563
    const int r8blocks = (NRB + 7) / 8;            // 12500

    // ---- CSR build ----
    hipMemsetAsync(deg, 0, 2 * NSEG * sizeof(int), stream);
    deg_all_kernel<<<dim3(eblocks, 3), 256, 0, stream>>>(ei_rr, ei_rb, ei_br, deg);
    scan1_kernel<<<SCAN_BLOCKS, 256, 0, stream>>>(deg, rowstart, bsum);
    scan2_kernel<<<1, 512, 0, stream>>>(bsum, SCAN_BLOCKS);
    scan3_inv_kernel<<<SCAN_BLOCKS, 256, 0, stream>>>(rowstart, bsum, deg, inv);
    fill_all_kernel<<<dim3(eblocks, 3), 256, 0, stream>>>(ei_rr, ei_rb, ei_br,
        rowstart, cursor, col_all);

    // ---- weight prep ----
    wprep_all_kernel<<<dim3(64, 9), 256, 0, stream>>>(
        Wl0_rb, Wl0_rr, Wr0_rr, Wr0_br, Wl0_br, Wr0_rb,
        Wl1_br, Wl1_rr, Wr1_rr, Wr1_br,
        b0_rr, b0_br, b1_rr, b1_br,
        WT1, WT2, WT3, WT4, bsum0, bsum1);

    // ---- layer 0 ----
    gemm_l0_kernel<<<dim3(gm64, 2), 256, 0, stream>>>(x_robot, x_ball, WT1, WT2,
        y_rb, y_rr, sr, y_br, sb, bsum0, b0_rb);
    gather_l0_kernel<<<dim3(r8blocks, 2), 256, 0, stream>>>(y_rr, y_br, sr, y_rb, sb,
        col_all, rowstart, inv, r, bl);

    // ---- layer 1 ----
    gemm_l1_kernel<<<dim3(gm64, 2), 256, 0, stream>>>(r, bl, WT3, WT4, z_rr, z_br,
        (float*)d_out, bsum1);
    gather64_dual_kernel<<<r8blocks, 256, 0, stream>>>(z_rr, z_br, col_all, rowstart,
        inv, (float*)d_out);
}